// Round 2
// baseline (470.632 us; speedup 1.0000x reference)
//
#include <hip/hip_runtime.h>
#include <hip/hip_bf16.h>

#define BSZ 4096
#define MAXLEN 200
#define EDIM 112
#define NPL 4   // K-split partial planes

typedef __attribute__((ext_vector_type(8))) short bf16x8;
typedef __attribute__((ext_vector_type(4))) float f32x4;

// f32 -> bf16 (RNE), bit-level
static __device__ __forceinline__ short f2bf(float f) {
    unsigned u = __float_as_uint(f);
    unsigned r = (u + 0x7fffu + ((u >> 16) & 1u)) >> 16;
    return (short)r;
}
static __device__ __forceinline__ float bf2f(short s) {
    return __uint_as_float(((unsigned)(unsigned short)s) << 16);
}
static __device__ __forceinline__ bf16x8 cvt8(float4 a, float4 b) {
    bf16x8 r;
    r[0] = f2bf(a.x); r[1] = f2bf(a.y); r[2] = f2bf(a.z); r[3] = f2bf(a.w);
    r[4] = f2bf(b.x); r[5] = f2bf(b.y); r[6] = f2bf(b.z); r[7] = f2bf(b.w);
    return r;
}
static __device__ __forceinline__ unsigned pack2(float a, float b) {
    return ((unsigned)f2bf(a) & 0xffffu) | ((unsigned)f2bf(b) << 16);
}

// Streaming f32 -> bf16; first `zgroups` 8-elem groups are zeros (PAD row).
__global__ __launch_bounds__(256) void f32_to_bf16(const float* __restrict__ src,
                                                   unsigned short* __restrict__ dst,
                                                   int ngroups, int zgroups) {
    int g = blockIdx.x * 256 + threadIdx.x;
    if (g >= ngroups) return;
    bf16x8 o;
    if (g < zgroups) {
        #pragma unroll
        for (int i = 0; i < 8; ++i) o[i] = 0;
    } else {
        const float* p = src + (size_t)(g - zgroups) * 8;
        float4 a = *(const float4*)p;
        float4 b = *(const float4*)(p + 4);
        o = cvt8(a, b);
    }
    *(bf16x8*)(dst + (size_t)g * 8) = o;
}

// bf16-table gather+mean-pool. One block per session; 4 waves x 4 rows/wave,
// 16 B/lane loads; Ebf row 0 is zeros (PAD).  Writes S and inits acc.
__global__ __launch_bounds__(256) void gather_pool_bf(const unsigned short* __restrict__ Ebf,
                                                      const int* __restrict__ items,
                                                      const float* __restrict__ slen,
                                                      float* __restrict__ S,
                                                      float* __restrict__ acc) {
    __shared__ float part[16][14][8];
    int wave = threadIdx.x >> 6;
    int lane = threadIdx.x & 63;
    int b = blockIdx.x;
    int rg = lane / 14;   // 0..3 for lanes 0..55
    int c  = lane % 14;
    const int* it = items + (size_t)b * MAXLEN + wave * 50;
    float a[8];
    #pragma unroll
    for (int e = 0; e < 8; ++e) a[e] = 0.f;
    if (lane < 56) {
        #pragma unroll
        for (int t = 0; t < 13; ++t) {
            int j = t * 4 + rg;
            int idx = 0;
            if (j < 50) idx = it[j];               // idx==0 -> zero row (PAD)
            bf16x8 v = *(const bf16x8*)(Ebf + (size_t)idx * EDIM + c * 8);
            #pragma unroll
            for (int e = 0; e < 8; ++e) a[e] += bf2f(v[e]);
        }
        #pragma unroll
        for (int e = 0; e < 8; ++e) part[wave * 4 + rg][c][e] = a[e];
    }
    __syncthreads();
    int tid = threadIdx.x;
    if (tid < EDIM) {
        int cc = tid >> 3, ee = tid & 7;
        float s = 0.f;
        #pragma unroll
        for (int g = 0; g < 16; ++g) s += part[g][cc][ee];
        s /= slen[b];
        S[(size_t)b * EDIM + tid]   = s;
        acc[(size_t)b * EDIM + tid] = s;
    }
}

// Load 8 consecutive f32 (if valid) -> bf16x8 fragment.
static __device__ __forceinline__ bf16x8 ldcvt(const float* p, bool valid) {
    if (valid) {
        float4 a = *(const float4*)(p);
        float4 b = *(const float4*)(p + 4);
        return cvt8(a, b);
    }
    bf16x8 z;
    #pragma unroll
    for (int i = 0; i < 8; ++i) z[i] = 0;
    return z;
}

// Layer-0 only: T1 = S @ W0^T -> Bsw fragment layout.  One wave per 16
// sessions, grid 256.
__global__ __launch_bounds__(64, 4) void fused_mid0(const float* __restrict__ Sin,
                                                    const float* __restrict__ W,
                                                    unsigned short* __restrict__ Bsw) {
    __shared__ unsigned short Ylds[16][136];  // bank-skewed rows
    int lane = threadIdx.x;
    int gw = blockIdx.x;          // 0..255
    int j0 = gw * 16;
    int nrow = lane & 15;
    int quad = lane >> 4;
    int ses = j0 + nrow;

    float4 v[7];
    const float4* p = (const float4*)(Sin + (size_t)ses * EDIM + quad * 28);
    #pragma unroll
    for (int i = 0; i < 7; ++i) v[i] = p[i];

    #pragma unroll
    for (int i = 0; i < 7; ++i) {
        uint2 pk;
        pk.x = pack2(v[i].x, v[i].y);
        pk.y = pack2(v[i].z, v[i].w);
        *(uint2*)&Ylds[nrow][quad * 28 + i * 4] = pk;
    }
    *(uint2*)&Ylds[nrow][112 + quad * 4] = make_uint2(0u, 0u);
    __syncthreads();

    bf16x8 aF[4];
    #pragma unroll
    for (int k32 = 0; k32 < 4; ++k32)
        aF[k32] = *(bf16x8*)&Ylds[nrow][k32 * 32 + quad * 8];

    f32x4 acc[7];
    #pragma unroll
    for (int t = 0; t < 7; ++t) acc[t] = (f32x4){0.f, 0.f, 0.f, 0.f};
    #pragma unroll
    for (int t = 0; t < 7; ++t) {
        const float* wr = W + (size_t)(16 * t + nrow) * EDIM;
        #pragma unroll
        for (int k32 = 0; k32 < 4; ++k32) {
            bf16x8 bF = ldcvt(wr + k32 * 32 + quad * 8, (k32 < 3) || (quad < 2));
            acc[t] = __builtin_amdgcn_mfma_f32_16x16x32_bf16(aF[k32], bF, acc[t], 0, 0, 0);
        }
    }

    int k32f = j0 >> 5;
    int qp = ((j0 >> 4) & 1) * 2 + (quad >> 1);
    int e0 = (quad & 1) * 4;
    #pragma unroll
    for (int t = 0; t < 7; ++t) {
        uint2 pk;
        pk.x = pack2(acc[t][0], acc[t][1]);
        pk.y = pack2(acc[t][2], acc[t][3]);
        *(uint2*)(Bsw + ((size_t)(k32f * 7 + t) * 64 + qp * 16 + nrow) * 8 + e0) = pk;
    }
}

// High-occupancy split-K GEMM: grid 1024 = 256 M-tiles x 4 K-quarters,
// 8 waves/block, 4 k32-steps per wave.  LDS footprint only 7.7 KB
// (ds-atomic reduction) -> up to 4 blocks/CU = 32 waves/CU for latency
// hiding.  Partials go to 4 f32 planes (contiguous 7 KB per block),
// merged by epi_mid / final_epilogue.
// AMODE 0: read f32 A, cvt in-register, side-write Asw.  AMODE 1: read Asw.
template <int AMODE>
__global__ __launch_bounds__(512, 4) void bg_gemm4(const float* __restrict__ Af,
                                                   unsigned short* __restrict__ Asw,
                                                   const unsigned short* __restrict__ Bsw,
                                                   float* __restrict__ Yp) {
    __shared__ float part[16][120];   // 7680 B; stride 120 keeps float4 alignment
    int tid = threadIdx.x;
    int w = tid >> 6;                 // 0..7
    int lane = tid & 63;
    int nrow = lane & 15;
    int quad = lane >> 4;
    int mtile = blockIdx.x & 255;
    int kq = blockIdx.x >> 8;         // 0..3

    if (tid < 480) ((float4*)part)[tid] = make_float4(0.f, 0.f, 0.f, 0.f);
    __syncthreads();

    f32x4 acc[7];
    #pragma unroll
    for (int t = 0; t < 7; ++t) acc[t] = (f32x4){0.f, 0.f, 0.f, 0.f};

    auto LOADA = [&](int k32) -> bf16x8 {
        size_t afrag = ((size_t)(mtile * 128 + k32) * 64 + lane) * 8;
        if (AMODE == 0) {
            const float* p = Af + (size_t)(mtile * 16 + nrow) * 4096 + k32 * 32 + quad * 8;
            float4 a0 = *(const float4*)p;
            float4 a1 = *(const float4*)(p + 4);
            bf16x8 r = cvt8(a0, a1);
            *(bf16x8*)(Asw + afrag) = r;       // side output for layers 2-3
            return r;
        } else {
            return *(const bf16x8*)(Asw + afrag);
        }
    };

    int k32 = kq * 32 + w * 4;
    bf16x8 aF = LOADA(k32);
    bf16x8 bF[7];
    {
        const unsigned short* bb = Bsw + ((size_t)k32 * 7 * 64 + lane) * 8;
        #pragma unroll
        for (int t = 0; t < 7; ++t) bF[t] = *(const bf16x8*)(bb + (size_t)t * 512);
    }
    #pragma unroll
    for (int ks = 0; ks < 3; ++ks) {
        bf16x8 aN = LOADA(k32 + 1);
        bf16x8 bN[7];
        const unsigned short* bb = Bsw + ((size_t)(k32 + 1) * 7 * 64 + lane) * 8;
        #pragma unroll
        for (int t = 0; t < 7; ++t) bN[t] = *(const bf16x8*)(bb + (size_t)t * 512);
        #pragma unroll
        for (int t = 0; t < 7; ++t)
            acc[t] = __builtin_amdgcn_mfma_f32_16x16x32_bf16(aF, bF[t], acc[t], 0, 0, 0);
        aF = aN;
        #pragma unroll
        for (int t = 0; t < 7; ++t) bF[t] = bN[t];
        ++k32;
    }
    #pragma unroll
    for (int t = 0; t < 7; ++t)
        acc[t] = __builtin_amdgcn_mfma_f32_16x16x32_bf16(aF, bF[t], acc[t], 0, 0, 0);

    // ---- cross-wave reduce via LDS f32 atomics: elem (m=quad*4+r, n=16t+nrow)
    #pragma unroll
    for (int t = 0; t < 7; ++t)
        #pragma unroll
        for (int r = 0; r < 4; ++r)
            atomicAdd(&part[quad * 4 + r][16 * t + nrow], acc[t][r]);
    __syncthreads();

    // ---- contiguous f32x4 store of the 16x112 tile into plane kq ----
    if (tid < 448) {
        int row16 = tid / 28;
        int col = (tid - row16 * 28) * 4;
        float4 v = *(const float4*)&part[row16][col];
        *(float4*)(Yp + (size_t)kq * BSZ * EDIM
                   + (size_t)(mtile * 16 + row16) * EDIM + col) = v;
    }
}

// Per-layer epilogue: sum NPL partials, d-scale, acc += Y/||Y||, and
// T' = Y @ W^T -> Bsw fragments.  One wave per 16 sessions, grid 256.
__global__ __launch_bounds__(64, 4) void epi_mid(const float* __restrict__ Yp,
                                                 const float* __restrict__ Dm,
                                                 float* __restrict__ accb,
                                                 const float* __restrict__ W,
                                                 unsigned short* __restrict__ Bsw) {
    __shared__ unsigned short Ylds[16][136];
    int lane = threadIdx.x;
    int gw = blockIdx.x;
    int j0 = gw * 16;
    int nrow = lane & 15;
    int quad = lane >> 4;
    int ses = j0 + nrow;

    float4 v[7];
    #pragma unroll
    for (int i = 0; i < 7; ++i) v[i] = make_float4(0.f, 0.f, 0.f, 0.f);
    #pragma unroll
    for (int pp = 0; pp < NPL; ++pp) {
        const float4* p = (const float4*)(Yp + (size_t)pp * BSZ * EDIM
                                          + (size_t)ses * EDIM + quad * 28);
        #pragma unroll
        for (int i = 0; i < 7; ++i) {
            float4 t = p[i];
            v[i].x += t.x; v[i].y += t.y; v[i].z += t.z; v[i].w += t.w;
        }
    }
    float d = Dm[(size_t)ses * (BSZ + 1)];
    float ss = 0.f;
    #pragma unroll
    for (int i = 0; i < 7; ++i) {
        v[i].x *= d; v[i].y *= d; v[i].z *= d; v[i].w *= d;
        ss += v[i].x * v[i].x + v[i].y * v[i].y + v[i].z * v[i].z + v[i].w * v[i].w;
    }
    ss += __shfl_xor(ss, 16, 64);
    ss += __shfl_xor(ss, 32, 64);
    float rinv = 1.f / fmaxf(sqrtf(ss), 1e-12f);
    float4* pa = (float4*)(accb + (size_t)ses * EDIM + quad * 28);
    #pragma unroll
    for (int i = 0; i < 7; ++i) {
        float4 a = pa[i];
        a.x += v[i].x * rinv; a.y += v[i].y * rinv;
        a.z += v[i].z * rinv; a.w += v[i].w * rinv;
        pa[i] = a;
    }

    // bf16 Y tile to LDS (cols 112..127 zeroed for K-padding)
    #pragma unroll
    for (int i = 0; i < 7; ++i) {
        uint2 pk;
        pk.x = pack2(v[i].x, v[i].y);
        pk.y = pack2(v[i].z, v[i].w);
        *(uint2*)&Ylds[nrow][quad * 28 + i * 4] = pk;
    }
    *(uint2*)&Ylds[nrow][112 + quad * 4] = make_uint2(0u, 0u);
    __syncthreads();

    bf16x8 aF[4];
    #pragma unroll
    for (int k32 = 0; k32 < 4; ++k32)
        aF[k32] = *(bf16x8*)&Ylds[nrow][k32 * 32 + quad * 8];

    f32x4 acc[7];
    #pragma unroll
    for (int t = 0; t < 7; ++t) acc[t] = (f32x4){0.f, 0.f, 0.f, 0.f};
    #pragma unroll
    for (int t = 0; t < 7; ++t) {
        const float* wr = W + (size_t)(16 * t + nrow) * EDIM;
        #pragma unroll
        for (int k32 = 0; k32 < 4; ++k32) {
            bf16x8 bF = ldcvt(wr + k32 * 32 + quad * 8, (k32 < 3) || (quad < 2));
            acc[t] = __builtin_amdgcn_mfma_f32_16x16x32_bf16(aF[k32], bF, acc[t], 0, 0, 0);
        }
    }

    int k32f = j0 >> 5;
    int qp = ((j0 >> 4) & 1) * 2 + (quad >> 1);
    int e0 = (quad & 1) * 4;
    #pragma unroll
    for (int t = 0; t < 7; ++t) {
        uint2 pk;
        pk.x = pack2(acc[t][0], acc[t][1]);
        pk.y = pack2(acc[t][2], acc[t][3]);
        *(uint2*)(Bsw + ((size_t)(k32f * 7 + t) * 64 + qp * 16 + nrow) * 8 + e0) = pk;
    }
}

// Final: sum NPL partials, d-scale, normalize, out = (acc + nv) / 4.
__global__ __launch_bounds__(256) void final_epilogue(const float* __restrict__ Yp,
                                                      const float* __restrict__ Dm,
                                                      const float* __restrict__ accb,
                                                      float* __restrict__ out) {
    int wave = threadIdx.x >> 6;
    int lane = threadIdx.x & 63;
    int b = blockIdx.x * 4 + wave;

    float2 v = make_float2(0.f, 0.f);
    size_t o2 = (size_t)b * 56 + lane;
    if (lane < 56) {
        #pragma unroll
        for (int p = 0; p < NPL; ++p) {
            float2 t = ((const float2*)(Yp + (size_t)p * BSZ * EDIM))[o2];
            v.x += t.x;
            v.y += t.y;
        }
    }
    float d = Dm[(size_t)b * (BSZ + 1)];
    v.x *= d; v.y *= d;
    float ss = v.x * v.x + v.y * v.y;
    #pragma unroll
    for (int off = 32; off; off >>= 1) ss += __shfl_xor(ss, off, 64);
    float nrm = fmaxf(sqrtf(ss), 1e-12f);
    if (lane < 56) {
        float2 a = ((const float2*)accb)[o2];
        ((float2*)out)[o2] = make_float2((a.x + v.x / nrm) * 0.25f,
                                         (a.y + v.y / nrm) * 0.25f);
    }
}

extern "C" void kernel_launch(void* const* d_in, const int* in_sizes, int n_in,
                              void* d_out, int out_size, void* d_ws, size_t ws_size,
                              hipStream_t stream) {
    (void)in_sizes; (void)n_in; (void)out_size; (void)ws_size;
    const float* emb   = (const float*)d_in[0];
    const float* Dm    = (const float*)d_in[1];
    const float* A     = (const float*)d_in[2];
    const float* slen  = (const float*)d_in[3];
    const float* Ws    = (const float*)d_in[4];
    const int*   items = (const int*)d_in[5];
    float* out = (float*)d_out;

    // workspace layout (16B-aligned), ~68.8 MB total
    char* w = (char*)d_ws;
    float* Sa   = (float*)w;                                      // 1835008 B
    float* accb = Sa + BSZ * EDIM;                                // 1835008 B
    float* Yp   = accb + BSZ * EDIM;                              // NPL x 1835008 B
    unsigned short* Bsw0 = (unsigned short*)(Yp + (size_t)NPL * BSZ * EDIM); // 917504 B
    unsigned short* Bsw1 = Bsw0 + (size_t)128 * 7 * 64 * 8;       // 917504 B
    unsigned short* Ebf  = Bsw1 + (size_t)128 * 7 * 64 * 8;       // 22400224 B
    unsigned short* Asw  = Ebf + (size_t)100001 * EDIM;           // 33554432 B

    // 1. embedding table -> bf16 (zero PAD row prepended)
    f32_to_bf16<<<5470, 256, 0, stream>>>(emb, Ebf, 1400014, 14);
    // 2. gather + mean-pool -> S, acc
    gather_pool_bf<<<BSZ, 256, 0, stream>>>(Ebf, items, slen, Sa, accb);
    // 3. T1 = S @ W0^T
    fused_mid0<<<256, 64, 0, stream>>>(Sa, Ws, Bsw0);
    // 4-9. three layers: split-K GEMM + epilogue
    bg_gemm4<0><<<1024, 512, 0, stream>>>(A, Asw, Bsw0, Yp);
    epi_mid<<<256, 64, 0, stream>>>(Yp, Dm, accb, Ws + (size_t)EDIM * EDIM, Bsw1);
    bg_gemm4<1><<<1024, 512, 0, stream>>>(nullptr, Asw, Bsw1, Yp);
    epi_mid<<<256, 64, 0, stream>>>(Yp, Dm, accb, Ws + (size_t)2 * EDIM * EDIM, Bsw0);
    bg_gemm4<1><<<1024, 512, 0, stream>>>(nullptr, Asw, Bsw0, Yp);
    final_epilogue<<<BSZ / 4, 256, 0, stream>>>(Yp, Dm, accb, out);
}

// Round 3
// 276.732 us; speedup vs baseline: 1.7007x; 1.7007x over previous
//
#include <hip/hip_runtime.h>
#include <hip/hip_bf16.h>

#define BSZ 4096
#define MAXLEN 200
#define EDIM 112
#define NPL 8   // K-split partial planes (one per kq block)

typedef __attribute__((ext_vector_type(8))) short bf16x8;
typedef __attribute__((ext_vector_type(4))) float f32x4;

// f32 -> bf16 (RNE), bit-level
static __device__ __forceinline__ short f2bf(float f) {
    unsigned u = __float_as_uint(f);
    unsigned r = (u + 0x7fffu + ((u >> 16) & 1u)) >> 16;
    return (short)r;
}
static __device__ __forceinline__ float bf2f(short s) {
    return __uint_as_float(((unsigned)(unsigned short)s) << 16);
}
static __device__ __forceinline__ bf16x8 cvt8(float4 a, float4 b) {
    bf16x8 r;
    r[0] = f2bf(a.x); r[1] = f2bf(a.y); r[2] = f2bf(a.z); r[3] = f2bf(a.w);
    r[4] = f2bf(b.x); r[5] = f2bf(b.y); r[6] = f2bf(b.z); r[7] = f2bf(b.w);
    return r;
}
static __device__ __forceinline__ unsigned pack2(float a, float b) {
    return ((unsigned)f2bf(a) & 0xffffu) | ((unsigned)f2bf(b) << 16);
}

// async global->LDS, 16 B per lane: LDS dest = wave-uniform base + lane*16.
static __device__ __forceinline__ void glds16(const unsigned short* g, unsigned short* l) {
    __builtin_amdgcn_global_load_lds(
        (__attribute__((address_space(1))) void*)(void*)g,
        (__attribute__((address_space(3))) void*)l, 16, 0, 0);
}

// Streaming f32 -> bf16; first `zgroups` 8-elem groups are zeros (PAD row).
__global__ __launch_bounds__(256) void f32_to_bf16(const float* __restrict__ src,
                                                   unsigned short* __restrict__ dst,
                                                   int ngroups, int zgroups) {
    int g = blockIdx.x * 256 + threadIdx.x;
    if (g >= ngroups) return;
    bf16x8 o;
    if (g < zgroups) {
        #pragma unroll
        for (int i = 0; i < 8; ++i) o[i] = 0;
    } else {
        const float* p = src + (size_t)(g - zgroups) * 8;
        float4 a = *(const float4*)p;
        float4 b = *(const float4*)(p + 4);
        o = cvt8(a, b);
    }
    *(bf16x8*)(dst + (size_t)g * 8) = o;
}

// bf16-table gather+mean-pool. One block per session; 4 waves x 4 rows/wave,
// 16 B/lane loads; Ebf row 0 is zeros (PAD).  Writes S and inits acc.
__global__ __launch_bounds__(256) void gather_pool_bf(const unsigned short* __restrict__ Ebf,
                                                      const int* __restrict__ items,
                                                      const float* __restrict__ slen,
                                                      float* __restrict__ S,
                                                      float* __restrict__ acc) {
    __shared__ float part[16][14][8];
    int wave = threadIdx.x >> 6;
    int lane = threadIdx.x & 63;
    int b = blockIdx.x;
    int rg = lane / 14;   // 0..3 for lanes 0..55
    int c  = lane % 14;
    const int* it = items + (size_t)b * MAXLEN + wave * 50;
    float a[8];
    #pragma unroll
    for (int e = 0; e < 8; ++e) a[e] = 0.f;
    if (lane < 56) {
        #pragma unroll
        for (int t = 0; t < 13; ++t) {
            int j = t * 4 + rg;
            int idx = 0;
            if (j < 50) idx = it[j];               // idx==0 -> zero row (PAD)
            bf16x8 v = *(const bf16x8*)(Ebf + (size_t)idx * EDIM + c * 8);
            #pragma unroll
            for (int e = 0; e < 8; ++e) a[e] += bf2f(v[e]);
        }
        #pragma unroll
        for (int e = 0; e < 8; ++e) part[wave * 4 + rg][c][e] = a[e];
    }
    __syncthreads();
    int tid = threadIdx.x;
    if (tid < EDIM) {
        int cc = tid >> 3, ee = tid & 7;
        float s = 0.f;
        #pragma unroll
        for (int g = 0; g < 16; ++g) s += part[g][cc][ee];
        s /= slen[b];
        S[(size_t)b * EDIM + tid]   = s;
        acc[(size_t)b * EDIM + tid] = s;
    }
}

// Load 8 consecutive f32 (if valid) -> bf16x8 fragment.
static __device__ __forceinline__ bf16x8 ldcvt(const float* p, bool valid) {
    if (valid) {
        float4 a = *(const float4*)(p);
        float4 b = *(const float4*)(p + 4);
        return cvt8(a, b);
    }
    bf16x8 z;
    #pragma unroll
    for (int i = 0; i < 8; ++i) z[i] = 0;
    return z;
}

// Layer-0 only: T1 = S @ W0^T -> Bsw fragment layout.  One wave per 16
// sessions, grid 256.
__global__ __launch_bounds__(64, 4) void fused_mid0(const float* __restrict__ Sin,
                                                    const float* __restrict__ W,
                                                    unsigned short* __restrict__ Bsw) {
    __shared__ unsigned short Ylds[16][136];  // bank-skewed rows
    int lane = threadIdx.x;
    int gw = blockIdx.x;          // 0..255
    int j0 = gw * 16;
    int nrow = lane & 15;
    int quad = lane >> 4;
    int ses = j0 + nrow;

    float4 v[7];
    const float4* p = (const float4*)(Sin + (size_t)ses * EDIM + quad * 28);
    #pragma unroll
    for (int i = 0; i < 7; ++i) v[i] = p[i];

    #pragma unroll
    for (int i = 0; i < 7; ++i) {
        uint2 pk;
        pk.x = pack2(v[i].x, v[i].y);
        pk.y = pack2(v[i].z, v[i].w);
        *(uint2*)&Ylds[nrow][quad * 28 + i * 4] = pk;
    }
    *(uint2*)&Ylds[nrow][112 + quad * 4] = make_uint2(0u, 0u);
    __syncthreads();

    bf16x8 aF[4];
    #pragma unroll
    for (int k32 = 0; k32 < 4; ++k32)
        aF[k32] = *(bf16x8*)&Ylds[nrow][k32 * 32 + quad * 8];

    f32x4 acc[7];
    #pragma unroll
    for (int t = 0; t < 7; ++t) acc[t] = (f32x4){0.f, 0.f, 0.f, 0.f};
    #pragma unroll
    for (int t = 0; t < 7; ++t) {
        const float* wr = W + (size_t)(16 * t + nrow) * EDIM;
        #pragma unroll
        for (int k32 = 0; k32 < 4; ++k32) {
            bf16x8 bF = ldcvt(wr + k32 * 32 + quad * 8, (k32 < 3) || (quad < 2));
            acc[t] = __builtin_amdgcn_mfma_f32_16x16x32_bf16(aF[k32], bF, acc[t], 0, 0, 0);
        }
    }

    int k32f = j0 >> 5;
    int qp = ((j0 >> 4) & 1) * 2 + (quad >> 1);
    int e0 = (quad & 1) * 4;
    #pragma unroll
    for (int t = 0; t < 7; ++t) {
        uint2 pk;
        pk.x = pack2(acc[t][0], acc[t][1]);
        pk.y = pack2(acc[t][2], acc[t][3]);
        *(uint2*)(Bsw + ((size_t)(k32f * 7 + t) * 64 + qp * 16 + nrow) * 8 + e0) = pk;
    }
}

// m97-style streaming GEMM: Y = A @ T.  grid 256 = 32 M-tiles(128 rows) x
// 8 K-chunks (K=512 each), 8 waves x 512 thr, 1 block/CU.
// Per K-step (BK=64 = 2 k32): cooperative global_load_lds staging of the
// A-tile (16 KB, fragment-linear Asw layout) and B-tile (14 KB contiguous
// Bsw) into LDS double-buffers; each wave computes its own 16-row sub-tile
// (14 MFMA); ONE barrier per step (compiler inserts the vmcnt drain).
// Waves own disjoint rows -> no cross-wave reduce; acc -> partial plane kq.
// AMODE 0: A staged from f32 via regs (cvt) + side-write Asw.  AMODE 1: glds.
template <int AMODE>
__global__ __launch_bounds__(512, 2) void bg_m97(const float* __restrict__ Af,
                                                 unsigned short* __restrict__ Asw,
                                                 const unsigned short* __restrict__ Bsw,
                                                 float* __restrict__ Yp) {
    __shared__ unsigned short Ab[2][16 * 512];   // 2 x 16 KB (16 frags)
    __shared__ unsigned short Bb[2][14 * 512];   // 2 x 14 KB (14 frags)
    int tid = threadIdx.x;
    int w = tid >> 6;                 // 0..7  (= sub-mtile owned by this wave)
    int lane = tid & 63;
    int nrow = lane & 15;
    int quad = lane >> 4;
    int mtile = blockIdx.x & 31;      // 128-row tile
    int kq = blockIdx.x >> 5;         // 0..7
    int M16 = mtile * 8 + w;          // 16-row tile index, 0..255

    f32x4 acc[7];
    #pragma unroll
    for (int t = 0; t < 7; ++t) acc[t] = (f32x4){0.f, 0.f, 0.f, 0.f};

    // stage K-step s into buffer buf
    auto STAGE = [&](int s, int buf) {
        int k32b = kq * 16 + s * 2;
        #pragma unroll
        for (int j = 0; j < 2; ++j) {
            int f = w * 2 + j;                    // frag = (sub-mtile w, kk j)
            size_t afrag = (((size_t)M16 * 128 + k32b + j) * 64 + lane) * 8;
            if (AMODE == 0) {
                const float* p = Af + (size_t)(M16 * 16 + nrow) * BSZ
                                 + (k32b + j) * 32 + quad * 8;
                float4 a0 = *(const float4*)p;
                float4 a1 = *(const float4*)(p + 4);
                bf16x8 r = cvt8(a0, a1);
                *(bf16x8*)&Ab[buf][f * 512 + lane * 8] = r;
                *(bf16x8*)(Asw + afrag) = r;      // side output for layers 2-3
            } else {
                glds16(Asw + afrag, &Ab[buf][f * 512]);
            }
        }
        if (w < 7) {
            #pragma unroll
            for (int j = 0; j < 2; ++j) {
                int c = w * 2 + j;                // chunk 0..13
                glds16(Bsw + (((size_t)k32b * 7 + c) * 64 + lane) * 8,
                       &Bb[buf][c * 512]);
            }
        }
    };

    STAGE(0, 0);
    __syncthreads();
    int cur = 0;
    #pragma unroll 1
    for (int s = 0; s < 8; ++s) {
        if (s < 7) STAGE(s + 1, cur ^ 1);
        #pragma unroll
        for (int kk = 0; kk < 2; ++kk) {
            bf16x8 aF = *(bf16x8*)&Ab[cur][(w * 2 + kk) * 512 + lane * 8];
            #pragma unroll
            for (int t = 0; t < 7; ++t) {
                bf16x8 bF = *(bf16x8*)&Bb[cur][(kk * 7 + t) * 512 + lane * 8];
                acc[t] = __builtin_amdgcn_mfma_f32_16x16x32_bf16(aF, bF, acc[t], 0, 0, 0);
            }
        }
        __syncthreads();
        cur ^= 1;
    }

    // C/D: (m = quad*4 + r, n = 16t + nrow) -> partial plane kq
    float* dst = Yp + (size_t)kq * BSZ * EDIM + (size_t)(M16 * 16) * EDIM;
    #pragma unroll
    for (int t = 0; t < 7; ++t)
        #pragma unroll
        for (int r = 0; r < 4; ++r)
            dst[(size_t)(quad * 4 + r) * EDIM + 16 * t + nrow] = acc[t][r];
}

// Per-layer epilogue: sum NPL partials, d-scale, acc += Y/||Y||, and
// T' = Y @ W^T -> Bsw fragments.  One wave per 16 sessions, grid 256.
__global__ __launch_bounds__(64, 4) void epi_mid(const float* __restrict__ Yp,
                                                 const float* __restrict__ Dm,
                                                 float* __restrict__ accb,
                                                 const float* __restrict__ W,
                                                 unsigned short* __restrict__ Bsw) {
    __shared__ unsigned short Ylds[16][136];
    int lane = threadIdx.x;
    int gw = blockIdx.x;
    int j0 = gw * 16;
    int nrow = lane & 15;
    int quad = lane >> 4;
    int ses = j0 + nrow;

    float4 v[7];
    #pragma unroll
    for (int i = 0; i < 7; ++i) v[i] = make_float4(0.f, 0.f, 0.f, 0.f);
    #pragma unroll
    for (int pp = 0; pp < NPL; ++pp) {
        const float4* p = (const float4*)(Yp + (size_t)pp * BSZ * EDIM
                                          + (size_t)ses * EDIM + quad * 28);
        #pragma unroll
        for (int i = 0; i < 7; ++i) {
            float4 t = p[i];
            v[i].x += t.x; v[i].y += t.y; v[i].z += t.z; v[i].w += t.w;
        }
    }
    float d = Dm[(size_t)ses * (BSZ + 1)];
    float ss = 0.f;
    #pragma unroll
    for (int i = 0; i < 7; ++i) {
        v[i].x *= d; v[i].y *= d; v[i].z *= d; v[i].w *= d;
        ss += v[i].x * v[i].x + v[i].y * v[i].y + v[i].z * v[i].z + v[i].w * v[i].w;
    }
    ss += __shfl_xor(ss, 16, 64);
    ss += __shfl_xor(ss, 32, 64);
    float rinv = 1.f / fmaxf(sqrtf(ss), 1e-12f);
    float4* pa = (float4*)(accb + (size_t)ses * EDIM + quad * 28);
    #pragma unroll
    for (int i = 0; i < 7; ++i) {
        float4 a = pa[i];
        a.x += v[i].x * rinv; a.y += v[i].y * rinv;
        a.z += v[i].z * rinv; a.w += v[i].w * rinv;
        pa[i] = a;
    }

    // bf16 Y tile to LDS (cols 112..127 zeroed for K-padding)
    #pragma unroll
    for (int i = 0; i < 7; ++i) {
        uint2 pk;
        pk.x = pack2(v[i].x, v[i].y);
        pk.y = pack2(v[i].z, v[i].w);
        *(uint2*)&Ylds[nrow][quad * 28 + i * 4] = pk;
    }
    *(uint2*)&Ylds[nrow][112 + quad * 4] = make_uint2(0u, 0u);
    __syncthreads();

    bf16x8 aF[4];
    #pragma unroll
    for (int k32 = 0; k32 < 4; ++k32)
        aF[k32] = *(bf16x8*)&Ylds[nrow][k32 * 32 + quad * 8];

    f32x4 acc[7];
    #pragma unroll
    for (int t = 0; t < 7; ++t) acc[t] = (f32x4){0.f, 0.f, 0.f, 0.f};
    #pragma unroll
    for (int t = 0; t < 7; ++t) {
        const float* wr = W + (size_t)(16 * t + nrow) * EDIM;
        #pragma unroll
        for (int k32 = 0; k32 < 4; ++k32) {
            bf16x8 bF = ldcvt(wr + k32 * 32 + quad * 8, (k32 < 3) || (quad < 2));
            acc[t] = __builtin_amdgcn_mfma_f32_16x16x32_bf16(aF[k32], bF, acc[t], 0, 0, 0);
        }
    }

    int k32f = j0 >> 5;
    int qp = ((j0 >> 4) & 1) * 2 + (quad >> 1);
    int e0 = (quad & 1) * 4;
    #pragma unroll
    for (int t = 0; t < 7; ++t) {
        uint2 pk;
        pk.x = pack2(acc[t][0], acc[t][1]);
        pk.y = pack2(acc[t][2], acc[t][3]);
        *(uint2*)(Bsw + ((size_t)(k32f * 7 + t) * 64 + qp * 16 + nrow) * 8 + e0) = pk;
    }
}

// Final: sum NPL partials, d-scale, normalize, out = (acc + nv) / 4.
__global__ __launch_bounds__(256) void final_epilogue(const float* __restrict__ Yp,
                                                      const float* __restrict__ Dm,
                                                      const float* __restrict__ accb,
                                                      float* __restrict__ out) {
    int wave = threadIdx.x >> 6;
    int lane = threadIdx.x & 63;
    int b = blockIdx.x * 4 + wave;

    float2 v = make_float2(0.f, 0.f);
    size_t o2 = (size_t)b * 56 + lane;
    if (lane < 56) {
        #pragma unroll
        for (int p = 0; p < NPL; ++p) {
            float2 t = ((const float2*)(Yp + (size_t)p * BSZ * EDIM))[o2];
            v.x += t.x;
            v.y += t.y;
        }
    }
    float d = Dm[(size_t)b * (BSZ + 1)];
    v.x *= d; v.y *= d;
    float ss = v.x * v.x + v.y * v.y;
    #pragma unroll
    for (int off = 32; off; off >>= 1) ss += __shfl_xor(ss, off, 64);
    float nrm = fmaxf(sqrtf(ss), 1e-12f);
    if (lane < 56) {
        float2 a = ((const float2*)accb)[o2];
        ((float2*)out)[o2] = make_float2((a.x + v.x / nrm) * 0.25f,
                                         (a.y + v.y / nrm) * 0.25f);
    }
}

extern "C" void kernel_launch(void* const* d_in, const int* in_sizes, int n_in,
                              void* d_out, int out_size, void* d_ws, size_t ws_size,
                              hipStream_t stream) {
    (void)in_sizes; (void)n_in; (void)out_size; (void)ws_size;
    const float* emb   = (const float*)d_in[0];
    const float* Dm    = (const float*)d_in[1];
    const float* A     = (const float*)d_in[2];
    const float* slen  = (const float*)d_in[3];
    const float* Ws    = (const float*)d_in[4];
    const int*   items = (const int*)d_in[5];
    float* out = (float*)d_out;

    // workspace layout (16B-aligned), ~76 MB total
    char* w = (char*)d_ws;
    float* Sa   = (float*)w;                                      // 1835008 B
    float* accb = Sa + BSZ * EDIM;                                // 1835008 B
    float* Yp   = accb + BSZ * EDIM;                              // NPL x 1835008 B
    unsigned short* Bsw0 = (unsigned short*)(Yp + (size_t)NPL * BSZ * EDIM); // 917504 B
    unsigned short* Bsw1 = Bsw0 + (size_t)128 * 7 * 64 * 8;       // 917504 B
    unsigned short* Ebf  = Bsw1 + (size_t)128 * 7 * 64 * 8;       // 22400224 B
    unsigned short* Asw  = Ebf + (size_t)100001 * EDIM;           // 33554432 B

    // 1. embedding table -> bf16 (zero PAD row prepended)
    f32_to_bf16<<<5470, 256, 0, stream>>>(emb, Ebf, 1400014, 14);
    // 2. gather + mean-pool -> S, acc
    gather_pool_bf<<<BSZ, 256, 0, stream>>>(Ebf, items, slen, Sa, accb);
    // 3. T1 = S @ W0^T
    fused_mid0<<<256, 64, 0, stream>>>(Sa, Ws, Bsw0);
    // 4-9. three layers: streaming GEMM + epilogue
    bg_m97<0><<<256, 512, 0, stream>>>(A, Asw, Bsw0, Yp);
    epi_mid<<<256, 64, 0, stream>>>(Yp, Dm, accb, Ws + (size_t)EDIM * EDIM, Bsw1);
    bg_m97<1><<<256, 512, 0, stream>>>(nullptr, Asw, Bsw1, Yp);
    epi_mid<<<256, 64, 0, stream>>>(Yp, Dm, accb, Ws + (size_t)2 * EDIM * EDIM, Bsw0);
    bg_m97<1><<<256, 512, 0, stream>>>(nullptr, Asw, Bsw0, Yp);
    final_epilogue<<<BSZ / 4, 256, 0, stream>>>(Yp, Dm, accb, out);
}

// Round 4
// 273.992 us; speedup vs baseline: 1.7177x; 1.0100x over previous
//
#include <hip/hip_runtime.h>
#include <hip/hip_bf16.h>

#define BSZ 4096
#define MAXLEN 200
#define EDIM 112
#define NPL 8   // K-split partial planes (one per kq block)

typedef __attribute__((ext_vector_type(8))) short bf16x8;
typedef __attribute__((ext_vector_type(4))) float f32x4;

// f32 -> bf16 (RNE), bit-level
static __device__ __forceinline__ short f2bf(float f) {
    unsigned u = __float_as_uint(f);
    unsigned r = (u + 0x7fffu + ((u >> 16) & 1u)) >> 16;
    return (short)r;
}
static __device__ __forceinline__ float bf2f(short s) {
    return __uint_as_float(((unsigned)(unsigned short)s) << 16);
}
static __device__ __forceinline__ bf16x8 cvt8(float4 a, float4 b) {
    bf16x8 r;
    r[0] = f2bf(a.x); r[1] = f2bf(a.y); r[2] = f2bf(a.z); r[3] = f2bf(a.w);
    r[4] = f2bf(b.x); r[5] = f2bf(b.y); r[6] = f2bf(b.z); r[7] = f2bf(b.w);
    return r;
}
static __device__ __forceinline__ unsigned pack2(float a, float b) {
    return ((unsigned)f2bf(a) & 0xffffu) | ((unsigned)f2bf(b) << 16);
}

// async global->LDS, 16 B per lane: LDS dest = wave-uniform base + lane*16.
static __device__ __forceinline__ void glds16(const unsigned short* g, unsigned short* l) {
    __builtin_amdgcn_global_load_lds(
        (__attribute__((address_space(1))) void*)(void*)g,
        (__attribute__((address_space(3))) void*)l, 16, 0, 0);
}

// Streaming f32 -> bf16; first `zgroups` 8-elem groups are zeros (PAD row).
__global__ __launch_bounds__(256) void f32_to_bf16(const float* __restrict__ src,
                                                   unsigned short* __restrict__ dst,
                                                   int ngroups, int zgroups) {
    int g = blockIdx.x * 256 + threadIdx.x;
    if (g >= ngroups) return;
    bf16x8 o;
    if (g < zgroups) {
        #pragma unroll
        for (int i = 0; i < 8; ++i) o[i] = 0;
    } else {
        const float* p = src + (size_t)(g - zgroups) * 8;
        float4 a = *(const float4*)p;
        float4 b = *(const float4*)(p + 4);
        o = cvt8(a, b);
    }
    *(bf16x8*)(dst + (size_t)g * 8) = o;
}

// A (f32 [4096x4096]) -> bf16 MFMA fragment layout (Asw), pure stream.
// thread = one 16-B output group: (M16, k32, lane); reads 32 B, writes 16 B.
__global__ __launch_bounds__(256) void cvtA(const float* __restrict__ Af,
                                            unsigned short* __restrict__ Asw) {
    int tid = threadIdx.x;
    int lane = tid & 63;
    int sub = tid >> 6;                 // 0..3
    int blk = blockIdx.x;               // 0..8191
    int M16 = blk >> 5;                 // 0..255
    int k32 = (blk & 31) * 4 + sub;     // 0..127
    int nrow = lane & 15, quad = lane >> 4;
    const float* p = Af + (size_t)(M16 * 16 + nrow) * BSZ + k32 * 32 + quad * 8;
    float4 a0 = *(const float4*)p;
    float4 a1 = *(const float4*)(p + 4);
    *(bf16x8*)(Asw + (((size_t)M16 * 128 + k32) * 64 + lane) * 8) = cvt8(a0, a1);
}

// bf16-table gather+mean-pool. One block per session; 4 waves x 4 rows/wave,
// 16 B/lane loads; Ebf row 0 is zeros (PAD).  Writes S and inits acc.
__global__ __launch_bounds__(256) void gather_pool_bf(const unsigned short* __restrict__ Ebf,
                                                      const int* __restrict__ items,
                                                      const float* __restrict__ slen,
                                                      float* __restrict__ S,
                                                      float* __restrict__ acc) {
    __shared__ float part[16][14][8];
    int wave = threadIdx.x >> 6;
    int lane = threadIdx.x & 63;
    int b = blockIdx.x;
    int rg = lane / 14;   // 0..3 for lanes 0..55
    int c  = lane % 14;
    const int* it = items + (size_t)b * MAXLEN + wave * 50;
    float a[8];
    #pragma unroll
    for (int e = 0; e < 8; ++e) a[e] = 0.f;
    if (lane < 56) {
        #pragma unroll
        for (int t = 0; t < 13; ++t) {
            int j = t * 4 + rg;
            int idx = 0;
            if (j < 50) idx = it[j];               // idx==0 -> zero row (PAD)
            bf16x8 v = *(const bf16x8*)(Ebf + (size_t)idx * EDIM + c * 8);
            #pragma unroll
            for (int e = 0; e < 8; ++e) a[e] += bf2f(v[e]);
        }
        #pragma unroll
        for (int e = 0; e < 8; ++e) part[wave * 4 + rg][c][e] = a[e];
    }
    __syncthreads();
    int tid = threadIdx.x;
    if (tid < EDIM) {
        int cc = tid >> 3, ee = tid & 7;
        float s = 0.f;
        #pragma unroll
        for (int g = 0; g < 16; ++g) s += part[g][cc][ee];
        s /= slen[b];
        S[(size_t)b * EDIM + tid]   = s;
        acc[(size_t)b * EDIM + tid] = s;
    }
}

// Load 8 consecutive f32 (if valid) -> bf16x8 fragment.
static __device__ __forceinline__ bf16x8 ldcvt(const float* p, bool valid) {
    if (valid) {
        float4 a = *(const float4*)(p);
        float4 b = *(const float4*)(p + 4);
        return cvt8(a, b);
    }
    bf16x8 z;
    #pragma unroll
    for (int i = 0; i < 8; ++i) z[i] = 0;
    return z;
}

// Layer-0 only: T1 = S @ W0^T -> Bsw fragment layout.  One wave per 16
// sessions, grid 256.
__global__ __launch_bounds__(64, 4) void fused_mid0(const float* __restrict__ Sin,
                                                    const float* __restrict__ W,
                                                    unsigned short* __restrict__ Bsw) {
    __shared__ unsigned short Ylds[16][136];  // bank-skewed rows
    int lane = threadIdx.x;
    int gw = blockIdx.x;          // 0..255
    int j0 = gw * 16;
    int nrow = lane & 15;
    int quad = lane >> 4;
    int ses = j0 + nrow;

    float4 v[7];
    const float4* p = (const float4*)(Sin + (size_t)ses * EDIM + quad * 28);
    #pragma unroll
    for (int i = 0; i < 7; ++i) v[i] = p[i];

    #pragma unroll
    for (int i = 0; i < 7; ++i) {
        uint2 pk;
        pk.x = pack2(v[i].x, v[i].y);
        pk.y = pack2(v[i].z, v[i].w);
        *(uint2*)&Ylds[nrow][quad * 28 + i * 4] = pk;
    }
    *(uint2*)&Ylds[nrow][112 + quad * 4] = make_uint2(0u, 0u);
    __syncthreads();

    bf16x8 aF[4];
    #pragma unroll
    for (int k32 = 0; k32 < 4; ++k32)
        aF[k32] = *(bf16x8*)&Ylds[nrow][k32 * 32 + quad * 8];

    f32x4 acc[7];
    #pragma unroll
    for (int t = 0; t < 7; ++t) acc[t] = (f32x4){0.f, 0.f, 0.f, 0.f};
    #pragma unroll
    for (int t = 0; t < 7; ++t) {
        const float* wr = W + (size_t)(16 * t + nrow) * EDIM;
        #pragma unroll
        for (int k32 = 0; k32 < 4; ++k32) {
            bf16x8 bF = ldcvt(wr + k32 * 32 + quad * 8, (k32 < 3) || (quad < 2));
            acc[t] = __builtin_amdgcn_mfma_f32_16x16x32_bf16(aF[k32], bF, acc[t], 0, 0, 0);
        }
    }

    int k32f = j0 >> 5;
    int qp = ((j0 >> 4) & 1) * 2 + (quad >> 1);
    int e0 = (quad & 1) * 4;
    #pragma unroll
    for (int t = 0; t < 7; ++t) {
        uint2 pk;
        pk.x = pack2(acc[t][0], acc[t][1]);
        pk.y = pack2(acc[t][2], acc[t][3]);
        *(uint2*)(Bsw + ((size_t)(k32f * 7 + t) * 64 + qp * 16 + nrow) * 8 + e0) = pk;
    }
}

// Deep-pipelined streaming GEMM: Y = A @ T.  grid 256 = 32 M-tiles(128 rows)
// x 8 K-chunks (K=512), 8 waves x 512 thr.
// 16 stages of BK=32; 4 LDS buffers (64 KB exactly); per wave per stage:
// 1 glds A-frag (its own sub-tile) + 1 glds B-frag (wave 7: dummy into pad
// slot so all waves issue 2 loads/stage -> uniform vmcnt counting).
// Counted s_waitcnt vmcnt(4) + raw s_barrier per stage: loads for the next
// 2-3 stages stay in flight ACROSS barriers -> continuous HBM stream, no
// stop-and-go drain.  Buffer reuse distance = 4 stages (no WAR race).
__global__ __launch_bounds__(512, 1) void bg_pipe(const unsigned short* __restrict__ Asw,
                                                  const unsigned short* __restrict__ Bsw,
                                                  float* __restrict__ Yp) {
    __shared__ unsigned short Ab[4][8 * 512];   // 4 x 8 KB
    __shared__ unsigned short Bb[4][8 * 512];   // 4 x 8 KB (slot 7 = pad)
    int tid = threadIdx.x;
    int w = tid >> 6;                 // 0..7 (= sub-mtile owned by this wave)
    int lane = tid & 63;
    int nrow = lane & 15;
    int quad = lane >> 4;
    int mtile = blockIdx.x & 31;      // 128-row tile
    int kq = blockIdx.x >> 5;         // 0..7
    int M16 = mtile * 8 + w;          // 16-row tile index, 0..255

    f32x4 acc[7];
    #pragma unroll
    for (int t = 0; t < 7; ++t) acc[t] = (f32x4){0.f, 0.f, 0.f, 0.f};

    // stage s (one k32) into buffer buf: 2 glds per wave, uniform
    auto STAGE = [&](int s, int buf) {
        int k32 = kq * 16 + s;
        glds16(Asw + (((size_t)M16 * 128 + k32) * 64 + lane) * 8,
               &Ab[buf][w * 512]);
        int c = (w < 7) ? w : 0;              // wave 7: dup frag 0 into pad
        glds16(Bsw + (((size_t)k32 * 7 + c) * 64 + lane) * 8,
               &Bb[buf][w * 512]);
    };

    STAGE(0, 0);
    STAGE(1, 1);
    STAGE(2, 2);
    #pragma unroll
    for (int s = 0; s < 16; ++s) {
        // retire stage s's 2 loads (keep stages s+1, s+2 in flight)
        if (s < 14)      asm volatile("s_waitcnt vmcnt(4)" ::: "memory");
        else if (s == 14) asm volatile("s_waitcnt vmcnt(2)" ::: "memory");
        else             asm volatile("s_waitcnt vmcnt(0)" ::: "memory");
        __builtin_amdgcn_s_barrier();
        if (s < 13) STAGE(s + 3, (s + 3) & 3);   // overwrites buf consumed at s-1
        int cur = s & 3;
        bf16x8 aF = *(bf16x8*)&Ab[cur][w * 512 + lane * 8];
        #pragma unroll
        for (int t = 0; t < 7; ++t) {
            bf16x8 bF = *(bf16x8*)&Bb[cur][t * 512 + lane * 8];
            acc[t] = __builtin_amdgcn_mfma_f32_16x16x32_bf16(aF, bF, acc[t], 0, 0, 0);
        }
    }

    // C/D: (m = quad*4 + r, n = 16t + nrow) -> partial plane kq
    float* dst = Yp + (size_t)kq * BSZ * EDIM + (size_t)(M16 * 16) * EDIM;
    #pragma unroll
    for (int t = 0; t < 7; ++t)
        #pragma unroll
        for (int r = 0; r < 4; ++r)
            dst[(size_t)(quad * 4 + r) * EDIM + 16 * t + nrow] = acc[t][r];
}

// Per-layer epilogue: sum NPL partials, d-scale, acc += Y/||Y||, and
// T' = Y @ W^T -> Bsw fragments.  One wave per 16 sessions, grid 256.
__global__ __launch_bounds__(64, 4) void epi_mid(const float* __restrict__ Yp,
                                                 const float* __restrict__ Dm,
                                                 float* __restrict__ accb,
                                                 const float* __restrict__ W,
                                                 unsigned short* __restrict__ Bsw) {
    __shared__ unsigned short Ylds[16][136];
    int lane = threadIdx.x;
    int gw = blockIdx.x;
    int j0 = gw * 16;
    int nrow = lane & 15;
    int quad = lane >> 4;
    int ses = j0 + nrow;

    float4 v[7];
    #pragma unroll
    for (int i = 0; i < 7; ++i) v[i] = make_float4(0.f, 0.f, 0.f, 0.f);
    #pragma unroll
    for (int pp = 0; pp < NPL; ++pp) {
        const float4* p = (const float4*)(Yp + (size_t)pp * BSZ * EDIM
                                          + (size_t)ses * EDIM + quad * 28);
        #pragma unroll
        for (int i = 0; i < 7; ++i) {
            float4 t = p[i];
            v[i].x += t.x; v[i].y += t.y; v[i].z += t.z; v[i].w += t.w;
        }
    }
    float d = Dm[(size_t)ses * (BSZ + 1)];
    float ss = 0.f;
    #pragma unroll
    for (int i = 0; i < 7; ++i) {
        v[i].x *= d; v[i].y *= d; v[i].z *= d; v[i].w *= d;
        ss += v[i].x * v[i].x + v[i].y * v[i].y + v[i].z * v[i].z + v[i].w * v[i].w;
    }
    ss += __shfl_xor(ss, 16, 64);
    ss += __shfl_xor(ss, 32, 64);
    float rinv = 1.f / fmaxf(sqrtf(ss), 1e-12f);
    float4* pa = (float4*)(accb + (size_t)ses * EDIM + quad * 28);
    #pragma unroll
    for (int i = 0; i < 7; ++i) {
        float4 a = pa[i];
        a.x += v[i].x * rinv; a.y += v[i].y * rinv;
        a.z += v[i].z * rinv; a.w += v[i].w * rinv;
        pa[i] = a;
    }

    // bf16 Y tile to LDS (cols 112..127 zeroed for K-padding)
    #pragma unroll
    for (int i = 0; i < 7; ++i) {
        uint2 pk;
        pk.x = pack2(v[i].x, v[i].y);
        pk.y = pack2(v[i].z, v[i].w);
        *(uint2*)&Ylds[nrow][quad * 28 + i * 4] = pk;
    }
    *(uint2*)&Ylds[nrow][112 + quad * 4] = make_uint2(0u, 0u);
    __syncthreads();

    bf16x8 aF[4];
    #pragma unroll
    for (int k32 = 0; k32 < 4; ++k32)
        aF[k32] = *(bf16x8*)&Ylds[nrow][k32 * 32 + quad * 8];

    f32x4 acc[7];
    #pragma unroll
    for (int t = 0; t < 7; ++t) acc[t] = (f32x4){0.f, 0.f, 0.f, 0.f};
    #pragma unroll
    for (int t = 0; t < 7; ++t) {
        const float* wr = W + (size_t)(16 * t + nrow) * EDIM;
        #pragma unroll
        for (int k32 = 0; k32 < 4; ++k32) {
            bf16x8 bF = ldcvt(wr + k32 * 32 + quad * 8, (k32 < 3) || (quad < 2));
            acc[t] = __builtin_amdgcn_mfma_f32_16x16x32_bf16(aF[k32], bF, acc[t], 0, 0, 0);
        }
    }

    int k32f = j0 >> 5;
    int qp = ((j0 >> 4) & 1) * 2 + (quad >> 1);
    int e0 = (quad & 1) * 4;
    #pragma unroll
    for (int t = 0; t < 7; ++t) {
        uint2 pk;
        pk.x = pack2(acc[t][0], acc[t][1]);
        pk.y = pack2(acc[t][2], acc[t][3]);
        *(uint2*)(Bsw + ((size_t)(k32f * 7 + t) * 64 + qp * 16 + nrow) * 8 + e0) = pk;
    }
}

// Final: sum NPL partials, d-scale, normalize, out = (acc + nv) / 4.
__global__ __launch_bounds__(256) void final_epilogue(const float* __restrict__ Yp,
                                                      const float* __restrict__ Dm,
                                                      const float* __restrict__ accb,
                                                      float* __restrict__ out) {
    int wave = threadIdx.x >> 6;
    int lane = threadIdx.x & 63;
    int b = blockIdx.x * 4 + wave;

    float2 v = make_float2(0.f, 0.f);
    size_t o2 = (size_t)b * 56 + lane;
    if (lane < 56) {
        #pragma unroll
        for (int p = 0; p < NPL; ++p) {
            float2 t = ((const float2*)(Yp + (size_t)p * BSZ * EDIM))[o2];
            v.x += t.x;
            v.y += t.y;
        }
    }
    float d = Dm[(size_t)b * (BSZ + 1)];
    v.x *= d; v.y *= d;
    float ss = v.x * v.x + v.y * v.y;
    #pragma unroll
    for (int off = 32; off; off >>= 1) ss += __shfl_xor(ss, off, 64);
    float nrm = fmaxf(sqrtf(ss), 1e-12f);
    if (lane < 56) {
        float2 a = ((const float2*)accb)[o2];
        ((float2*)out)[o2] = make_float2((a.x + v.x / nrm) * 0.25f,
                                         (a.y + v.y / nrm) * 0.25f);
    }
}

extern "C" void kernel_launch(void* const* d_in, const int* in_sizes, int n_in,
                              void* d_out, int out_size, void* d_ws, size_t ws_size,
                              hipStream_t stream) {
    (void)in_sizes; (void)n_in; (void)out_size; (void)ws_size;
    const float* emb   = (const float*)d_in[0];
    const float* Dm    = (const float*)d_in[1];
    const float* A     = (const float*)d_in[2];
    const float* slen  = (const float*)d_in[3];
    const float* Ws    = (const float*)d_in[4];
    const int*   items = (const int*)d_in[5];
    float* out = (float*)d_out;

    // workspace layout (16B-aligned), ~76 MB total
    char* w = (char*)d_ws;
    float* Sa   = (float*)w;                                      // 1835008 B
    float* accb = Sa + BSZ * EDIM;                                // 1835008 B
    float* Yp   = accb + BSZ * EDIM;                              // NPL x 1835008 B
    unsigned short* Bsw0 = (unsigned short*)(Yp + (size_t)NPL * BSZ * EDIM); // 917504 B
    unsigned short* Bsw1 = Bsw0 + (size_t)128 * 7 * 64 * 8;       // 917504 B
    unsigned short* Ebf  = Bsw1 + (size_t)128 * 7 * 64 * 8;       // 22400224 B
    unsigned short* Asw  = Ebf + (size_t)100001 * EDIM;           // 33554432 B

    // 1. embedding table -> bf16 (zero PAD row prepended)
    f32_to_bf16<<<5470, 256, 0, stream>>>(emb, Ebf, 1400014, 14);
    // 2. gather + mean-pool -> S, acc
    gather_pool_bf<<<BSZ, 256, 0, stream>>>(Ebf, items, slen, Sa, accb);
    // 3. A -> bf16 fragments (once; reused by all three layers)
    cvtA<<<8192, 256, 0, stream>>>(A, Asw);
    // 4. T1 = S @ W0^T
    fused_mid0<<<256, 64, 0, stream>>>(Sa, Ws, Bsw0);
    // 5-9. three layers: pipelined streaming GEMM + epilogue
    bg_pipe<<<256, 512, 0, stream>>>(Asw, Bsw0, Yp);
    epi_mid<<<256, 64, 0, stream>>>(Yp, Dm, accb, Ws + (size_t)EDIM * EDIM, Bsw1);
    bg_pipe<<<256, 512, 0, stream>>>(Asw, Bsw1, Yp);
    epi_mid<<<256, 64, 0, stream>>>(Yp, Dm, accb, Ws + (size_t)2 * EDIM * EDIM, Bsw0);
    bg_pipe<<<256, 512, 0, stream>>>(Asw, Bsw0, Yp);
    final_epilogue<<<BSZ / 4, 256, 0, stream>>>(Yp, Dm, accb, out);
}